// Round 4
// baseline (291.318 us; speedup 1.0000x reference)
//
#include <hip/hip_runtime.h>
#include <stdint.h>

#define DEMB 1024
#define NHEAD 16
#define DHEAD 64
#define SEQ 2048
#define MROWS 4096  // B*S

typedef __bf16 bf16x8 __attribute__((ext_vector_type(8)));
typedef float f32x4 __attribute__((ext_vector_type(4)));
typedef unsigned short u16;

#define LOG2E 1.44269504088896340736f

__device__ __forceinline__ u16 f2b(float f) {
  uint32_t u = __builtin_bit_cast(uint32_t, f);
  u += 0x7fffu + ((u >> 16) & 1u);
  return (u16)(u >> 16);
}

__device__ __forceinline__ f32x4 mfma16(bf16x8 a, bf16x8 b, f32x4 c) {
  return __builtin_amdgcn_mfma_f32_16x16x32_bf16(a, b, c, 0, 0, 0);
}

__device__ __forceinline__ void gload_lds16(const void* g, void* l) {
  __builtin_amdgcn_global_load_lds(
      (__attribute__((address_space(1))) unsigned int*)(g),
      (__attribute__((address_space(3))) unsigned int*)(l), 16, 0, 0);
}

// 2-phase tile barrier: drain this wave's global_load_lds (vmcnt) AND its
// ds_writes (lgkmcnt) before the raw barrier.
__device__ __forceinline__ void tile_barrier() {
  __builtin_amdgcn_sched_barrier(0);
  asm volatile("s_waitcnt vmcnt(0) lgkmcnt(0)" ::: "memory");
  __builtin_amdgcn_s_barrier();
  __builtin_amdgcn_sched_barrier(0);
}

// fused fp32->bf16 convert of three regions (sizes all multiples of 4)
__global__ void cvt3_f32_bf16(const float* __restrict__ a, int na,
                              const float* __restrict__ b, int nb,
                              const float* __restrict__ c, int nc,
                              u16* __restrict__ da, u16* __restrict__ db,
                              u16* __restrict__ dc) {
  const int total = (na + nb + nc) >> 2;
  const int stride = gridDim.x * blockDim.x;
  for (int t = blockIdx.x * blockDim.x + threadIdx.x; t < total; t += stride) {
    int i = t << 2;
    const float* s;
    u16* d;
    if (i < na) {
      s = a + i; d = da + i;
    } else if (i < na + nb) {
      s = b + (i - na); d = db + (i - na);
    } else {
      s = c + (i - na - nb); d = dc + (i - na - nb);
    }
    float4 f = *(const float4*)s;
    ushort4 o;
    o.x = f2b(f.x); o.y = f2b(f.y); o.z = f2b(f.z); o.w = f2b(f.w);
    *(ushort4*)d = o;
  }
}

// NT GEMM: C[m,n] = sum_k A[m,k]*B[n,k] (+bias[n]).
// BM=BN=128, BK=64, 4 waves (2x2), swizzled LDS via pre-swizzled global src.
// EPI==0: scatter to Q/K/V [B,H,S,Dh] bf16 (Q pre-scaled by 0.125*log2e so
//         attention softmax runs in the log2 domain).
// EPI==1: write fp32 C[m*N+n].
template <int EPI>
__global__ __launch_bounds__(256, 2) void gemm_nt(
    const u16* __restrict__ A, const u16* __restrict__ Bw,
    const float* __restrict__ bias, int K, int N,
    u16* __restrict__ q_out, u16* __restrict__ k_out, u16* __restrict__ v_out,
    float* __restrict__ f_out) {
  __shared__ __align__(16) u16 As[128 * 64];
  __shared__ __align__(16) u16 Bs[128 * 64];
  const int tid = threadIdx.x;
  const int w = tid >> 6;
  const int lane = tid & 63;
  const int wm = w >> 1, wn = w & 1;
  const int m0 = blockIdx.y * 128, n0 = blockIdx.x * 128;
  const int l16 = lane & 15, lg = lane >> 4;
  const int st_row = lane >> 3, st_slot = lane & 7;

  f32x4 acc[4][4] = {};

  for (int k0 = 0; k0 < K; k0 += 64) {
#pragma unroll
    for (int i = 0; i < 4; ++i) {
      const int chunk = (w << 2) | i;
      const int row = (chunk << 3) | st_row;
      const int scol = (st_slot ^ (row & 7)) << 3;
      gload_lds16(A + (size_t)(m0 + row) * K + k0 + scol, (char*)As + (chunk << 10));
      gload_lds16(Bw + (size_t)(n0 + row) * K + k0 + scol, (char*)Bs + (chunk << 10));
    }
    __syncthreads();
#pragma unroll
    for (int ks = 0; ks < 2; ++ks) {
      bf16x8 af[4], bfr[4];
#pragma unroll
      for (int mi = 0; mi < 4; ++mi) {
        const int row = wm * 64 + mi * 16 + l16;
        const int cb = ((ks << 6) | (lg << 4)) ^ ((row & 7) << 4);
        af[mi] = *(const bf16x8*)((const char*)As + row * 128 + cb);
      }
#pragma unroll
      for (int ni = 0; ni < 4; ++ni) {
        const int row = wn * 64 + ni * 16 + l16;
        const int cb = ((ks << 6) | (lg << 4)) ^ ((row & 7) << 4);
        bfr[ni] = *(const bf16x8*)((const char*)Bs + row * 128 + cb);
      }
#pragma unroll
      for (int mi = 0; mi < 4; ++mi)
#pragma unroll
        for (int ni = 0; ni < 4; ++ni)
          acc[mi][ni] = mfma16(af[mi], bfr[ni], acc[mi][ni]);
    }
    __syncthreads();
  }

#pragma unroll
  for (int ni = 0; ni < 4; ++ni) {
    const int n = n0 + wn * 64 + ni * 16 + l16;
    const float bv = bias[n];
    if (EPI == 0) {
      const int part = n >> 10;
      const int hh = (n >> 6) & 15;
      const int dh = n & 63;
      const float scl = (part == 0) ? (0.125f * LOG2E) : 1.0f;
      u16* dst = (part == 0) ? q_out : (part == 1) ? k_out : v_out;
#pragma unroll
      for (int mi = 0; mi < 4; ++mi) {
#pragma unroll
        for (int i = 0; i < 4; ++i) {
          const int m = m0 + wm * 64 + mi * 16 + (lg << 2) + i;
          const int bq = m >> 11, s = m & 2047;
          dst[((size_t)((bq << 4) | hh) * SEQ + s) * DHEAD + dh] = f2b((acc[mi][ni][i] + bv) * scl);
        }
      }
    } else {
#pragma unroll
      for (int mi = 0; mi < 4; ++mi)
#pragma unroll
        for (int i = 0; i < 4; ++i) {
          const int m = m0 + wm * 64 + mi * 16 + (lg << 2) + i;
          f_out[(size_t)m * N + n] = acc[mi][ni][i] + bv;
        }
    }
  }
}

// ---- attention ----
__device__ __forceinline__ void stage_k(const u16* __restrict__ Kb, size_t base,
                                        int jt, u16* Ks, int w, int lane) {
  const int st_row = lane >> 3, st_slot = lane & 7;
#pragma unroll
  for (int i = 0; i < 2; ++i) {
    const int chunk = (w << 1) | i;
    const int row = (chunk << 3) | st_row;
    const int scol = (st_slot ^ (row & 7)) << 3;
    gload_lds16(Kb + base + (size_t)(jt * 64 + row) * DHEAD + scol, (char*)Ks + (chunk << 10));
  }
}

// V transpose into swizzled LDS Vt[d][kv]: thread holds V[vr][c0..c0+7] in regs,
// scatters 8 scalar writes per half.
__device__ __forceinline__ void write_vt(u16* Vt, uint4 va, uint4 vb, int tid) {
  const int c0 = (tid & 7) << 3;
  const int vr0 = tid >> 3;
  const int vr1 = 32 + (tid >> 3);
  const u16* pa = (const u16*)&va;
  const u16* pb = (const u16*)&vb;
#pragma unroll
  for (int e = 0; e < 8; ++e) {
    const int rt = c0 + e;
    const int sw = (rt & 7) << 4;
    *(u16*)((char*)Vt + rt * 128 + ((vr0 << 1) ^ sw)) = pa[e];
    *(u16*)((char*)Vt + rt * 128 + ((vr1 << 1) ^ sw)) = pb[e];
  }
}

// QBLK=128 (wave owns 32 q-rows as 2 row-frags), KVBLK=64, double-buffered.
// Q pre-scaled by 0.125*log2e => softmax in log2 domain (exp2, no mul).
__global__ __launch_bounds__(256, 4) void attn_fwd(
    const u16* __restrict__ Qb, const u16* __restrict__ Kb,
    const u16* __restrict__ Vb, u16* __restrict__ Ob,
    const int* __restrict__ amask) {
  __shared__ __align__(16) u16 Ks[2][64 * 64];
  __shared__ __align__(16) u16 Vt[2][64 * 64];
  __shared__ __align__(16) u16 Ps[4][16 * 64];
  const int tid = threadIdx.x;
  const int w = tid >> 6, lane = tid & 63;
  const int l16 = lane & 15, lg = lane >> 4;
  const int bh = blockIdx.x;
  const int qi = (gridDim.y - 1) - blockIdx.y;  // heavy tiles dispatch first
  const int qblk0 = qi * 128;
  const size_t base = (size_t)bh * (SEQ * DHEAD);
  const bool causal = (amask[0] != 0);
  const int ntiles = causal ? (2 * qi + 2) : (SEQ / 64);

  // Q fragments: 2 row-frags x 2 k-slices
  bf16x8 qf[2][2];
#pragma unroll
  for (int rf = 0; rf < 2; ++rf) {
    const u16* qp = Qb + base + (size_t)(qblk0 + w * 32 + rf * 16 + l16) * DHEAD + (lg << 3);
    qf[rf][0] = *(const bf16x8*)qp;
    qf[rf][1] = *(const bf16x8*)(qp + 32);
  }

  float mrow[2][4], lrow[2][4];
  f32x4 oacc[2][4] = {};
#pragma unroll
  for (int rf = 0; rf < 2; ++rf)
#pragma unroll
    for (int i = 0; i < 4; ++i) { mrow[rf][i] = -1e30f; lrow[rf][i] = 0.f; }

  const int vcol = (tid & 7) << 3;
  const int vrow = tid >> 3;

  // prologue: stage tile 0
  stage_k(Kb, base, 0, Ks[0], w, lane);
  {
    uint4 va = *(const uint4*)(Vb + base + (size_t)vrow * DHEAD + vcol);
    uint4 vb2 = *(const uint4*)(Vb + base + (size_t)(32 + vrow) * DHEAD + vcol);
    write_vt(Vt[0], va, vb2, tid);
  }
  tile_barrier();

  int cur = 0;
  for (int j = 0; j < ntiles; ++j) {
    const u16* Kcur = Ks[cur];
    const u16* Vcur = Vt[cur];
    const bool pre = (j + 1 < ntiles);
    uint4 vna = {}, vnb = {};
    if (pre) {
      stage_k(Kb, base, j + 1, Ks[cur ^ 1], w, lane);
      const u16* vsrc = Vb + base + (size_t)(j + 1) * 64 * DHEAD;
      vna = *(const uint4*)(vsrc + (size_t)vrow * DHEAD + vcol);
      vnb = *(const uint4*)(vsrc + (size_t)(32 + vrow) * DHEAD + vcol);
    }

    // S = Q K^T : 2 row-frags x 4 kv-frags (K-tile reads shared across rf)
    f32x4 sv[2][4];
    __builtin_amdgcn_s_setprio(1);
#pragma unroll
    for (int nf = 0; nf < 4; ++nf) {
      const int row = nf * 16 + l16;
      const int sw = (row & 7) << 4;
      bf16x8 kf0 = *(const bf16x8*)((const char*)Kcur + row * 128 + ((lg << 4) ^ sw));
      bf16x8 kf1 = *(const bf16x8*)((const char*)Kcur + row * 128 + ((64 | (lg << 4)) ^ sw));
#pragma unroll
      for (int rf = 0; rf < 2; ++rf) {
        f32x4 s = {};
        s = mfma16(qf[rf][0], kf0, s);
        s = mfma16(qf[rf][1], kf1, s);
        sv[rf][nf] = s;
      }
    }
    __builtin_amdgcn_s_setprio(0);

    // causal mask needed only on the last two tiles of a block
    if (causal && (j + 2 >= ntiles)) {
#pragma unroll
      for (int rf = 0; rf < 2; ++rf)
#pragma unroll
        for (int nf = 0; nf < 4; ++nf)
#pragma unroll
          for (int i = 0; i < 4; ++i) {
            const int qrow = qblk0 + w * 32 + rf * 16 + (lg << 2) + i;
            const int col = j * 64 + nf * 16 + l16;
            if (col > qrow) sv[rf][nf][i] = -1e30f;
          }
    }

    // softmax per row-frag; Ps buffer (2KB/wave) reused sequentially
    bf16x8 pa[2][2];
#pragma unroll
    for (int rf = 0; rf < 2; ++rf) {
      float tmax[4];
#pragma unroll
      for (int i = 0; i < 4; ++i)
        tmax[i] = fmaxf(fmaxf(sv[rf][0][i], sv[rf][1][i]),
                        fmaxf(sv[rf][2][i], sv[rf][3][i]));
#pragma unroll
      for (int d = 1; d < 16; d <<= 1)
#pragma unroll
        for (int i = 0; i < 4; ++i)
          tmax[i] = fmaxf(tmax[i], __shfl_xor(tmax[i], d));

      int grow = 0;
#pragma unroll
      for (int i = 0; i < 4; ++i) grow |= (tmax[i] > mrow[rf][i] + 8.0f) ? 1 : 0;
      if (__any(grow)) {
#pragma unroll
        for (int i = 0; i < 4; ++i) {
          const float mnew = fmaxf(mrow[rf][i], tmax[i]);
          const float corr = exp2f(mrow[rf][i] - mnew);
          mrow[rf][i] = mnew;
          lrow[rf][i] *= corr;
#pragma unroll
          for (int df = 0; df < 4; ++df) oacc[rf][df][i] *= corr;
        }
      }

      float psum[4] = {0.f, 0.f, 0.f, 0.f};
      u16 pb[4][4];
#pragma unroll
      for (int nf = 0; nf < 4; ++nf)
#pragma unroll
        for (int i = 0; i < 4; ++i) {
          const float p = exp2f(sv[rf][nf][i] - mrow[rf][i]);
          psum[i] += p;
          pb[nf][i] = f2b(p);
        }
#pragma unroll
      for (int d = 1; d < 16; d <<= 1)
#pragma unroll
        for (int i = 0; i < 4; ++i)
          psum[i] += __shfl_xor(psum[i], d);
#pragma unroll
      for (int i = 0; i < 4; ++i) lrow[rf][i] += psum[i];

      u16* Pw = &Ps[w][0];
#pragma unroll
      for (int nf = 0; nf < 4; ++nf)
#pragma unroll
        for (int i = 0; i < 4; ++i) {
          const int row = (lg << 2) | i;
          const int cb = ((nf * 16 + l16) << 1) ^ ((row & 7) << 4);
          *(u16*)((char*)Pw + row * 128 + cb) = pb[nf][i];
        }
      {
        const int sw = (l16 & 7) << 4;
        pa[rf][0] = *(const bf16x8*)((const char*)Pw + l16 * 128 + ((lg << 4) ^ sw));
        pa[rf][1] = *(const bf16x8*)((const char*)Pw + l16 * 128 + ((64 | (lg << 4)) ^ sw));
      }
    }

    // PV: V-tile reads shared across both row-frags
    __builtin_amdgcn_s_setprio(1);
#pragma unroll
    for (int df = 0; df < 4; ++df) {
      const int row = df * 16 + l16;
      const int sw = (row & 7) << 4;
      bf16x8 vf0 = *(const bf16x8*)((const char*)Vcur + row * 128 + ((lg << 4) ^ sw));
      bf16x8 vf1 = *(const bf16x8*)((const char*)Vcur + row * 128 + ((64 | (lg << 4)) ^ sw));
#pragma unroll
      for (int rf = 0; rf < 2; ++rf) {
        oacc[rf][df] = mfma16(pa[rf][0], vf0, oacc[rf][df]);
        oacc[rf][df] = mfma16(pa[rf][1], vf1, oacc[rf][df]);
      }
    }
    __builtin_amdgcn_s_setprio(0);

    if (pre) {
      write_vt(Vt[cur ^ 1], vna, vnb, tid);
      tile_barrier();
    }
    cur ^= 1;
  }

  // epilogue
  const int b = bh >> 4, h = bh & 15;
#pragma unroll
  for (int rf = 0; rf < 2; ++rf)
#pragma unroll
    for (int i = 0; i < 4; ++i) {
      const float inv = 1.0f / lrow[rf][i];
      const int q = qblk0 + w * 32 + rf * 16 + (lg << 2) + i;
      u16* orow = Ob + (size_t)(b * SEQ + q) * DEMB + h * DHEAD;
#pragma unroll
      for (int df = 0; df < 4; ++df)
        orow[df * 16 + l16] = f2b(oacc[rf][df][i] * inv);
    }
}

extern "C" void kernel_launch(void* const* d_in, const int* in_sizes, int n_in,
                              void* d_out, int out_size, void* d_ws, size_t ws_size,
                              hipStream_t stream) {
  const float* x = (const float*)d_in[0];
  const float* w_in = (const float*)d_in[1];
  const float* b_in = (const float*)d_in[2];
  const float* w_out = (const float*)d_in[3];
  const float* b_out = (const float*)d_in[4];
  const int* amask = (const int*)d_in[5];
  float* out = (float*)d_out;

  u16* xb = (u16*)d_ws;
  u16* wib = xb + (size_t)MROWS * DEMB;
  u16* wob = wib + (size_t)3 * DEMB * DEMB;
  u16* Qb = wob + (size_t)DEMB * DEMB;
  u16* Kb = Qb + (size_t)MROWS * DEMB;
  u16* Vb = Kb + (size_t)MROWS * DEMB;
  u16* Ab = xb;  // attn output reuses x-bf16 region

  cvt3_f32_bf16<<<2048, 256, 0, stream>>>(x, MROWS * DEMB, w_in, 3 * DEMB * DEMB,
                                          w_out, DEMB * DEMB, xb, wib, wob);

  gemm_nt<0><<<dim3(24, 32), 256, 0, stream>>>(xb, wib, b_in, DEMB, 3 * DEMB,
                                               Qb, Kb, Vb, nullptr);
  attn_fwd<<<dim3(32, SEQ / 128), 256, 0, stream>>>(Qb, Kb, Vb, Ab, amask);
  gemm_nt<1><<<dim3(8, 32), 256, 0, stream>>>(Ab, wob, b_out, DEMB, DEMB,
                                              nullptr, nullptr, nullptr, out);
}

// Round 5
// 159.314 us; speedup vs baseline: 1.8286x; 1.8286x over previous
//
#include <hip/hip_runtime.h>
#include <stdint.h>

#define DEMB 1024
#define NHEAD 16
#define DHEAD 64
#define SEQ 2048
#define MROWS 4096  // B*S

typedef __bf16 bf16x8 __attribute__((ext_vector_type(8)));
typedef float f32x4 __attribute__((ext_vector_type(4)));
typedef unsigned short u16;

#define LOG2E 1.44269504088896340736f

__device__ __forceinline__ u16 f2b(float f) {
  uint32_t u = __builtin_bit_cast(uint32_t, f);
  u += 0x7fffu + ((u >> 16) & 1u);
  return (u16)(u >> 16);
}

__device__ __forceinline__ f32x4 mfma16(bf16x8 a, bf16x8 b, f32x4 c) {
  return __builtin_amdgcn_mfma_f32_16x16x32_bf16(a, b, c, 0, 0, 0);
}

__device__ __forceinline__ void gload_lds16(const void* g, void* l) {
  __builtin_amdgcn_global_load_lds(
      (__attribute__((address_space(1))) unsigned int*)(g),
      (__attribute__((address_space(3))) unsigned int*)(l), 16, 0, 0);
}

// 2-phase tile barrier: drain this wave's global_load_lds (vmcnt) AND its
// ds_writes (lgkmcnt) before the raw barrier.
__device__ __forceinline__ void tile_barrier() {
  __builtin_amdgcn_sched_barrier(0);
  asm volatile("s_waitcnt vmcnt(0) lgkmcnt(0)" ::: "memory");
  __builtin_amdgcn_s_barrier();
  __builtin_amdgcn_sched_barrier(0);
}

// fused fp32->bf16 convert of three regions (sizes all multiples of 4)
__global__ void cvt3_f32_bf16(const float* __restrict__ a, int na,
                              const float* __restrict__ b, int nb,
                              const float* __restrict__ c, int nc,
                              u16* __restrict__ da, u16* __restrict__ db,
                              u16* __restrict__ dc) {
  const int total = (na + nb + nc) >> 2;
  const int stride = gridDim.x * blockDim.x;
  for (int t = blockIdx.x * blockDim.x + threadIdx.x; t < total; t += stride) {
    int i = t << 2;
    const float* s;
    u16* d;
    if (i < na) {
      s = a + i; d = da + i;
    } else if (i < na + nb) {
      s = b + (i - na); d = db + (i - na);
    } else {
      s = c + (i - na - nb); d = dc + (i - na - nb);
    }
    float4 f = *(const float4*)s;
    ushort4 o;
    o.x = f2b(f.x); o.y = f2b(f.y); o.z = f2b(f.z); o.w = f2b(f.w);
    *(ushort4*)d = o;
  }
}

// NT GEMM: C[m,n] = sum_k A[m,k]*B[n,k] (+bias[n]).
// EPI==0: scatter to Q/K/V [B,H,S,Dh] bf16 (Q pre-scaled by 0.125*log2e so
//         attention softmax runs in the log2 domain).
// EPI==1: write fp32 C[m*N+n].
template <int EPI>
__global__ __launch_bounds__(256, 2) void gemm_nt(
    const u16* __restrict__ A, const u16* __restrict__ Bw,
    const float* __restrict__ bias, int K, int N,
    u16* __restrict__ q_out, u16* __restrict__ k_out, u16* __restrict__ v_out,
    float* __restrict__ f_out) {
  __shared__ __align__(16) u16 As[128 * 64];
  __shared__ __align__(16) u16 Bs[128 * 64];
  const int tid = threadIdx.x;
  const int w = tid >> 6;
  const int lane = tid & 63;
  const int wm = w >> 1, wn = w & 1;
  const int m0 = blockIdx.y * 128, n0 = blockIdx.x * 128;
  const int l16 = lane & 15, lg = lane >> 4;
  const int st_row = lane >> 3, st_slot = lane & 7;

  f32x4 acc[4][4] = {};

  for (int k0 = 0; k0 < K; k0 += 64) {
#pragma unroll
    for (int i = 0; i < 4; ++i) {
      const int chunk = (w << 2) | i;
      const int row = (chunk << 3) | st_row;
      const int scol = (st_slot ^ (row & 7)) << 3;
      gload_lds16(A + (size_t)(m0 + row) * K + k0 + scol, (char*)As + (chunk << 10));
      gload_lds16(Bw + (size_t)(n0 + row) * K + k0 + scol, (char*)Bs + (chunk << 10));
    }
    __syncthreads();
#pragma unroll
    for (int ks = 0; ks < 2; ++ks) {
      bf16x8 af[4], bfr[4];
#pragma unroll
      for (int mi = 0; mi < 4; ++mi) {
        const int row = wm * 64 + mi * 16 + l16;
        const int cb = ((ks << 6) | (lg << 4)) ^ ((row & 7) << 4);
        af[mi] = *(const bf16x8*)((const char*)As + row * 128 + cb);
      }
#pragma unroll
      for (int ni = 0; ni < 4; ++ni) {
        const int row = wn * 64 + ni * 16 + l16;
        const int cb = ((ks << 6) | (lg << 4)) ^ ((row & 7) << 4);
        bfr[ni] = *(const bf16x8*)((const char*)Bs + row * 128 + cb);
      }
#pragma unroll
      for (int mi = 0; mi < 4; ++mi)
#pragma unroll
        for (int ni = 0; ni < 4; ++ni)
          acc[mi][ni] = mfma16(af[mi], bfr[ni], acc[mi][ni]);
    }
    __syncthreads();
  }

#pragma unroll
  for (int ni = 0; ni < 4; ++ni) {
    const int n = n0 + wn * 64 + ni * 16 + l16;
    const float bv = bias[n];
    if (EPI == 0) {
      const int part = n >> 10;
      const int hh = (n >> 6) & 15;
      const int dh = n & 63;
      const float scl = (part == 0) ? (0.125f * LOG2E) : 1.0f;
      u16* dst = (part == 0) ? q_out : (part == 1) ? k_out : v_out;
#pragma unroll
      for (int mi = 0; mi < 4; ++mi) {
#pragma unroll
        for (int i = 0; i < 4; ++i) {
          const int m = m0 + wm * 64 + mi * 16 + (lg << 2) + i;
          const int bq = m >> 11, s = m & 2047;
          dst[((size_t)((bq << 4) | hh) * SEQ + s) * DHEAD + dh] = f2b((acc[mi][ni][i] + bv) * scl);
        }
      }
    } else {
#pragma unroll
      for (int mi = 0; mi < 4; ++mi)
#pragma unroll
        for (int i = 0; i < 4; ++i) {
          const int m = m0 + wm * 64 + mi * 16 + (lg << 2) + i;
          f_out[(size_t)m * N + n] = acc[mi][ni][i] + bv;
        }
    }
  }
}

// ---- attention ----
__device__ __forceinline__ void stage_k(const u16* __restrict__ Kb, size_t base,
                                        int jt, u16* Ks, int w, int lane) {
  const int st_row = lane >> 3, st_slot = lane & 7;
#pragma unroll
  for (int i = 0; i < 2; ++i) {
    const int chunk = (w << 1) | i;
    const int row = (chunk << 3) | st_row;
    const int scol = (st_slot ^ (row & 7)) << 3;
    gload_lds16(Kb + base + (size_t)(jt * 64 + row) * DHEAD + scol, (char*)Ks + (chunk << 10));
  }
}

// Vt swizzle: spreads BOTH d (rt) and kv (vr) into the bank index so the
// scalar transpose writes are 2-way (free) instead of 16-way conflicted.
__device__ __forceinline__ int vswz(int rt) {
  return ((rt & 7) ^ ((rt >> 3) & 7)) << 4;
}

// V transpose into swizzled LDS Vt[d][kv]: thread holds V[vr][c0..c0+7] in
// regs, scatters 8 scalar writes per half. Write bank = f(vr low bits, rt)
// -> 32 distinct banks per instruction (2 lanes/bank, free per m136).
__device__ __forceinline__ void write_vt(u16* Vt, uint4 va, uint4 vb, int tid) {
  const int c0 = (tid & 7) << 3;
  const int vr0 = tid >> 3;
  const int vr1 = 32 + (tid >> 3);
  const u16* pa = (const u16*)&va;
  const u16* pb = (const u16*)&vb;
#pragma unroll
  for (int e = 0; e < 8; ++e) {
    const int rt = c0 + e;
    const int sw = vswz(rt);
    *(u16*)((char*)Vt + rt * 128 + ((vr0 << 1) ^ sw)) = pa[e];
    *(u16*)((char*)Vt + rt * 128 + ((vr1 << 1) ^ sw)) = pb[e];
  }
}

// QBLK=64 (round-3 structure: no spill), KVBLK=64, double-buffered.
// 1-D grid decoded as (xcd, bh-chunk, qi-descending) for L2 locality + LPT.
__global__ __launch_bounds__(256, 4) void attn_fwd(
    const u16* __restrict__ Qb, const u16* __restrict__ Kb,
    const u16* __restrict__ Vb, u16* __restrict__ Ob,
    const int* __restrict__ amask) {
  __shared__ __align__(16) u16 Ks[2][64 * 64];
  __shared__ __align__(16) u16 Vt[2][64 * 64];
  __shared__ __align__(16) u16 Ps[4][16 * 64];
  const int tid = threadIdx.x;
  const int w = tid >> 6, lane = tid & 63;
  const int l16 = lane & 15, lg = lane >> 4;

  // id -> (bh, qi): same-XCD blocks share 4 heads' K/V (1MB -> L2-resident);
  // qi descending => heavy blocks first (LPT, kills the causal tail).
  const int id = blockIdx.x;
  const int xcd = id & 7;
  const int j = id >> 3;
  const int bh = (xcd << 2) | (j & 3);
  const int qi = 31 - (j >> 2);

  const int qblk0 = qi * 64;
  const size_t base = (size_t)bh * (SEQ * DHEAD);
  const bool causal = (amask[0] != 0);
  const int ntiles = causal ? (qi + 1) : (SEQ / 64);

  // Q fragments (Q pre-scaled by 0.125*log2e in GEMM epilogue)
  bf16x8 qf[2];
  {
    const u16* qp = Qb + base + (size_t)(qblk0 + w * 16 + l16) * DHEAD + (lg << 3);
    qf[0] = *(const bf16x8*)qp;
    qf[1] = *(const bf16x8*)(qp + 32);
  }

  float mrow[4] = {-1e30f, -1e30f, -1e30f, -1e30f};
  float lrow[4] = {0.f, 0.f, 0.f, 0.f};
  f32x4 oacc[4] = {};

  const int vcol = (tid & 7) << 3;
  const int vrow = tid >> 3;

  // prologue: stage tile 0
  stage_k(Kb, base, 0, Ks[0], w, lane);
  {
    uint4 va = *(const uint4*)(Vb + base + (size_t)vrow * DHEAD + vcol);
    uint4 vb2 = *(const uint4*)(Vb + base + (size_t)(32 + vrow) * DHEAD + vcol);
    write_vt(Vt[0], va, vb2, tid);
  }
  tile_barrier();

  int cur = 0;
  for (int j2 = 0; j2 < ntiles; ++j2) {
    const u16* Kcur = Ks[cur];
    const u16* Vcur = Vt[cur];
    const bool pre = (j2 + 1 < ntiles);
    uint4 vna = {}, vnb = {};
    if (pre) {
      stage_k(Kb, base, j2 + 1, Ks[cur ^ 1], w, lane);
      const u16* vsrc = Vb + base + (size_t)(j2 + 1) * 64 * DHEAD;
      vna = *(const uint4*)(vsrc + (size_t)vrow * DHEAD + vcol);
      vnb = *(const uint4*)(vsrc + (size_t)(32 + vrow) * DHEAD + vcol);
    }

    // S = Q K^T (per wave: 16 q-rows x 64 kv), log2 domain
    f32x4 sv[4];
    __builtin_amdgcn_s_setprio(1);
#pragma unroll
    for (int nf = 0; nf < 4; ++nf) {
      const int row = nf * 16 + l16;
      const int sw = (row & 7) << 4;
      bf16x8 kf0 = *(const bf16x8*)((const char*)Kcur + row * 128 + ((lg << 4) ^ sw));
      bf16x8 kf1 = *(const bf16x8*)((const char*)Kcur + row * 128 + ((64 | (lg << 4)) ^ sw));
      f32x4 s = {};
      s = mfma16(qf[0], kf0, s);
      s = mfma16(qf[1], kf1, s);
      sv[nf] = s;
    }
    __builtin_amdgcn_s_setprio(0);

    if (causal && (j2 == qi)) {
#pragma unroll
      for (int nf = 0; nf < 4; ++nf)
#pragma unroll
        for (int i = 0; i < 4; ++i) {
          const int qrow = (w << 4) + (lg << 2) + i;
          const int col = nf * 16 + l16;
          if (col > qrow) sv[nf][i] = -1e30f;
        }
    }

    // row max over this tile (in-reg + 16-lane shuffle tree)
    float tmax[4];
#pragma unroll
    for (int i = 0; i < 4; ++i)
      tmax[i] = fmaxf(fmaxf(sv[0][i], sv[1][i]), fmaxf(sv[2][i], sv[3][i]));
#pragma unroll
    for (int d = 1; d < 16; d <<= 1)
#pragma unroll
      for (int i = 0; i < 4; ++i)
        tmax[i] = fmaxf(tmax[i], __shfl_xor(tmax[i], d));

    // defer-max (T13): only rescale when some row's max grew by > 8 (log2)
    int grow = 0;
#pragma unroll
    for (int i = 0; i < 4; ++i) grow |= (tmax[i] > mrow[i] + 8.0f) ? 1 : 0;
    if (__any(grow)) {
#pragma unroll
      for (int i = 0; i < 4; ++i) {
        const float mnew = fmaxf(mrow[i], tmax[i]);
        const float corr = exp2f(mrow[i] - mnew);
        mrow[i] = mnew;
        lrow[i] *= corr;
#pragma unroll
        for (int df = 0; df < 4; ++df) oacc[df][i] *= corr;
      }
    }

    float psum[4] = {0.f, 0.f, 0.f, 0.f};
    u16 pb[4][4];
#pragma unroll
    for (int nf = 0; nf < 4; ++nf)
#pragma unroll
      for (int i = 0; i < 4; ++i) {
        const float p = exp2f(sv[nf][i] - mrow[i]);
        psum[i] += p;
        pb[nf][i] = f2b(p);
      }
#pragma unroll
    for (int d = 1; d < 16; d <<= 1)
#pragma unroll
      for (int i = 0; i < 4; ++i)
        psum[i] += __shfl_xor(psum[i], d);
#pragma unroll
    for (int i = 0; i < 4; ++i) lrow[i] += psum[i];

    // P -> per-wave LDS (swizzled), re-read as A-fragments
    u16* Pw = &Ps[w][0];
#pragma unroll
    for (int nf = 0; nf < 4; ++nf)
#pragma unroll
      for (int i = 0; i < 4; ++i) {
        const int row = (lg << 2) | i;
        const int cb = ((nf * 16 + l16) << 1) ^ ((row & 7) << 4);
        *(u16*)((char*)Pw + row * 128 + cb) = pb[nf][i];
      }
    bf16x8 pa0, pa1;
    {
      const int sw = (l16 & 7) << 4;
      pa0 = *(const bf16x8*)((const char*)Pw + l16 * 128 + ((lg << 4) ^ sw));
      pa1 = *(const bf16x8*)((const char*)Pw + l16 * 128 + ((64 | (lg << 4)) ^ sw));
    }

    // PV from transposed V tile (vswz-swizzled reads)
    __builtin_amdgcn_s_setprio(1);
#pragma unroll
    for (int df = 0; df < 4; ++df) {
      const int row = df * 16 + l16;
      const int sw = vswz(row);
      bf16x8 vf0 = *(const bf16x8*)((const char*)Vcur + row * 128 + ((lg << 4) ^ sw));
      bf16x8 vf1 = *(const bf16x8*)((const char*)Vcur + row * 128 + ((64 | (lg << 4)) ^ sw));
      oacc[df] = mfma16(pa0, vf0, oacc[df]);
      oacc[df] = mfma16(pa1, vf1, oacc[df]);
    }
    __builtin_amdgcn_s_setprio(0);

    if (pre) {
      write_vt(Vt[cur ^ 1], vna, vnb, tid);
      tile_barrier();
    }
    cur ^= 1;
  }

  // epilogue: O /= l, write bf16 to [B,S,H*Dh]
  const int b = bh >> 4, h = bh & 15;
#pragma unroll
  for (int i = 0; i < 4; ++i) {
    const float inv = 1.0f / lrow[i];
    const int q = qblk0 + (w << 4) + (lg << 2) + i;
    u16* orow = Ob + (size_t)(b * SEQ + q) * DEMB + h * DHEAD;
#pragma unroll
    for (int df = 0; df < 4; ++df)
      orow[df * 16 + l16] = f2b(oacc[df][i] * inv);
  }
}

extern "C" void kernel_launch(void* const* d_in, const int* in_sizes, int n_in,
                              void* d_out, int out_size, void* d_ws, size_t ws_size,
                              hipStream_t stream) {
  const float* x = (const float*)d_in[0];
  const float* w_in = (const float*)d_in[1];
  const float* b_in = (const float*)d_in[2];
  const float* w_out = (const float*)d_in[3];
  const float* b_out = (const float*)d_in[4];
  const int* amask = (const int*)d_in[5];
  float* out = (float*)d_out;

  u16* xb = (u16*)d_ws;
  u16* wib = xb + (size_t)MROWS * DEMB;
  u16* wob = wib + (size_t)3 * DEMB * DEMB;
  u16* Qb = wob + (size_t)DEMB * DEMB;
  u16* Kb = Qb + (size_t)MROWS * DEMB;
  u16* Vb = Kb + (size_t)MROWS * DEMB;
  u16* Ab = xb;  // attn output reuses x-bf16 region

  cvt3_f32_bf16<<<2048, 256, 0, stream>>>(x, MROWS * DEMB, w_in, 3 * DEMB * DEMB,
                                          w_out, DEMB * DEMB, xb, wib, wob);

  gemm_nt<0><<<dim3(24, 32), 256, 0, stream>>>(xb, wib, b_in, DEMB, 3 * DEMB,
                                               Qb, Kb, Vb, nullptr);
  attn_fwd<<<1024, 256, 0, stream>>>(Qb, Kb, Vb, Ab, amask);
  gemm_nt<1><<<dim3(8, 32), 256, 0, stream>>>(Ab, wob, b_out, DEMB, DEMB,
                                              nullptr, nullptr, nullptr, out);
}

// Round 6
// 118.590 us; speedup vs baseline: 2.4565x; 1.3434x over previous
//
#include <hip/hip_runtime.h>
#include <stdint.h>

#define DEMB 1024
#define NHEAD 16
#define DHEAD 64
#define SEQ 2048
#define MROWS 4096  // B*S

typedef __bf16 bf16x8 __attribute__((ext_vector_type(8)));
typedef float f32x4 __attribute__((ext_vector_type(4)));
typedef unsigned short u16;

#define LOG2E 1.44269504088896340736f

__device__ __forceinline__ u16 f2b(float f) {
  uint32_t u = __builtin_bit_cast(uint32_t, f);
  u += 0x7fffu + ((u >> 16) & 1u);
  return (u16)(u >> 16);
}

__device__ __forceinline__ f32x4 mfma16(bf16x8 a, bf16x8 b, f32x4 c) {
  return __builtin_amdgcn_mfma_f32_16x16x32_bf16(a, b, c, 0, 0, 0);
}

__device__ __forceinline__ void gload_lds16(const void* g, void* l) {
  __builtin_amdgcn_global_load_lds(
      (__attribute__((address_space(1))) unsigned int*)(g),
      (__attribute__((address_space(3))) unsigned int*)(l), 16, 0, 0);
}

// 2-phase tile barrier: drain this wave's global_load_lds (vmcnt) AND its
// ds_writes (lgkmcnt) before the raw barrier.
__device__ __forceinline__ void tile_barrier() {
  __builtin_amdgcn_sched_barrier(0);
  asm volatile("s_waitcnt vmcnt(0) lgkmcnt(0)" ::: "memory");
  __builtin_amdgcn_s_barrier();
  __builtin_amdgcn_sched_barrier(0);
}

// fused fp32->bf16 convert of three regions (sizes all multiples of 4)
__global__ void cvt3_f32_bf16(const float* __restrict__ a, int na,
                              const float* __restrict__ b, int nb,
                              const float* __restrict__ c, int nc,
                              u16* __restrict__ da, u16* __restrict__ db,
                              u16* __restrict__ dc) {
  const int total = (na + nb + nc) >> 2;
  const int stride = gridDim.x * blockDim.x;
  for (int t = blockIdx.x * blockDim.x + threadIdx.x; t < total; t += stride) {
    int i = t << 2;
    const float* s;
    u16* d;
    if (i < na) {
      s = a + i; d = da + i;
    } else if (i < na + nb) {
      s = b + (i - na); d = db + (i - na);
    } else {
      s = c + (i - na - nb); d = dc + (i - na - nb);
    }
    float4 f = *(const float4*)s;
    ushort4 o;
    o.x = f2b(f.x); o.y = f2b(f.y); o.z = f2b(f.z); o.w = f2b(f.w);
    *(ushort4*)d = o;
  }
}

// NT GEMM: C[m,n] = sum_k A[m,k]*B[n,k] (+bias[n]).
// EPI==0: scatter to Q/K/V [B,H,S,Dh] bf16 (Q pre-scaled by 0.125*log2e so
//         attention softmax runs in the log2 domain).
// EPI==1: write fp32 C[m*N+n].
template <int EPI>
__global__ __launch_bounds__(256, 2) void gemm_nt(
    const u16* __restrict__ A, const u16* __restrict__ Bw,
    const float* __restrict__ bias, int K, int N,
    u16* __restrict__ q_out, u16* __restrict__ k_out, u16* __restrict__ v_out,
    float* __restrict__ f_out) {
  __shared__ __align__(16) u16 As[128 * 64];
  __shared__ __align__(16) u16 Bs[128 * 64];
  const int tid = threadIdx.x;
  const int w = tid >> 6;
  const int lane = tid & 63;
  const int wm = w >> 1, wn = w & 1;
  const int m0 = blockIdx.y * 128, n0 = blockIdx.x * 128;
  const int l16 = lane & 15, lg = lane >> 4;
  const int st_row = lane >> 3, st_slot = lane & 7;

  f32x4 acc[4][4] = {};

  for (int k0 = 0; k0 < K; k0 += 64) {
#pragma unroll
    for (int i = 0; i < 4; ++i) {
      const int chunk = (w << 2) | i;
      const int row = (chunk << 3) | st_row;
      const int scol = (st_slot ^ (row & 7)) << 3;
      gload_lds16(A + (size_t)(m0 + row) * K + k0 + scol, (char*)As + (chunk << 10));
      gload_lds16(Bw + (size_t)(n0 + row) * K + k0 + scol, (char*)Bs + (chunk << 10));
    }
    __syncthreads();
#pragma unroll
    for (int ks = 0; ks < 2; ++ks) {
      bf16x8 af[4], bfr[4];
#pragma unroll
      for (int mi = 0; mi < 4; ++mi) {
        const int row = wm * 64 + mi * 16 + l16;
        const int cb = ((ks << 6) | (lg << 4)) ^ ((row & 7) << 4);
        af[mi] = *(const bf16x8*)((const char*)As + row * 128 + cb);
      }
#pragma unroll
      for (int ni = 0; ni < 4; ++ni) {
        const int row = wn * 64 + ni * 16 + l16;
        const int cb = ((ks << 6) | (lg << 4)) ^ ((row & 7) << 4);
        bfr[ni] = *(const bf16x8*)((const char*)Bs + row * 128 + cb);
      }
#pragma unroll
      for (int mi = 0; mi < 4; ++mi)
#pragma unroll
        for (int ni = 0; ni < 4; ++ni)
          acc[mi][ni] = mfma16(af[mi], bfr[ni], acc[mi][ni]);
    }
    __syncthreads();
  }

#pragma unroll
  for (int ni = 0; ni < 4; ++ni) {
    const int n = n0 + wn * 64 + ni * 16 + l16;
    const float bv = bias[n];
    if (EPI == 0) {
      const int part = n >> 10;
      const int hh = (n >> 6) & 15;
      const int dh = n & 63;
      const float scl = (part == 0) ? (0.125f * LOG2E) : 1.0f;
      u16* dst = (part == 0) ? q_out : (part == 1) ? k_out : v_out;
#pragma unroll
      for (int mi = 0; mi < 4; ++mi) {
#pragma unroll
        for (int i = 0; i < 4; ++i) {
          const int m = m0 + wm * 64 + mi * 16 + (lg << 2) + i;
          const int bq = m >> 11, s = m & 2047;
          dst[((size_t)((bq << 4) | hh) * SEQ + s) * DHEAD + dh] = f2b((acc[mi][ni][i] + bv) * scl);
        }
      }
    } else {
#pragma unroll
      for (int mi = 0; mi < 4; ++mi)
#pragma unroll
        for (int i = 0; i < 4; ++i) {
          const int m = m0 + wm * 64 + mi * 16 + (lg << 2) + i;
          f_out[(size_t)m * N + n] = acc[mi][ni][i] + bv;
        }
    }
  }
}

// ---- attention ----
__device__ __forceinline__ void stage_k(const u16* __restrict__ Kb, size_t base,
                                        int jt, u16* Ks, int w, int lane) {
  const int st_row = lane >> 3, st_slot = lane & 7;
#pragma unroll
  for (int i = 0; i < 2; ++i) {
    const int chunk = (w << 1) | i;
    const int row = (chunk << 3) | st_row;
    const int scol = (st_slot ^ (row & 7)) << 3;
    gload_lds16(Kb + base + (size_t)(jt * 64 + row) * DHEAD + scol, (char*)Ks + (chunk << 10));
  }
}

// Vt swizzle: spreads BOTH d (rt) and kv (vr) into the bank index so the
// scalar transpose writes are 2-way (free) instead of 16-way conflicted.
__device__ __forceinline__ int vswz(int rt) {
  return ((rt & 7) ^ ((rt >> 3) & 7)) << 4;
}

// V transpose into swizzled LDS Vt[d][kv].
__device__ __forceinline__ void write_vt(u16* Vt, uint4 va, uint4 vb, int tid) {
  const int c0 = (tid & 7) << 3;
  const int vr0 = tid >> 3;
  const int vr1 = 32 + (tid >> 3);
  const u16* pa = (const u16*)&va;
  const u16* pb = (const u16*)&vb;
#pragma unroll
  for (int e = 0; e < 8; ++e) {
    const int rt = c0 + e;
    const int sw = vswz(rt);
    *(u16*)((char*)Vt + rt * 128 + ((vr0 << 1) ^ sw)) = pa[e];
    *(u16*)((char*)Vt + rt * 128 + ((vr1 << 1) ^ sw)) = pb[e];
  }
}

// Swapped-operand flash attention. QBLK=64 (4 waves x 16 q), KVBLK=64, dbuf.
// S^T = mfma(K,Q): lane owns ONE q (l16); kv lives in regs (nf,lg,i) ->
// in-lane softmax reductions (2 shuffles instead of 4-step chains).
// Each block processes the PAIR of q-tiles (31-p, p): exactly 33 causal
// iterations per block -> perfectly balanced grid of 512 uniform blocks.
__global__ __launch_bounds__(256, 4) void attn_fwd(
    const u16* __restrict__ Qb, const u16* __restrict__ Kb,
    const u16* __restrict__ Vb, u16* __restrict__ Ob,
    const int* __restrict__ amask) {
  __shared__ __align__(16) u16 Ks[2][64 * 64];
  __shared__ __align__(16) u16 Vt[2][64 * 64];
  __shared__ __align__(16) uint32_t Ps[4][16 * 32];  // packed P, per wave
  const int tid = threadIdx.x;
  const int w = tid >> 6, lane = tid & 63;
  const int l16 = lane & 15, lg = lane >> 4;

  // 512 blocks: xcd-major so 4 heads' K/V stay L2-resident per XCD.
  const int id = blockIdx.x;
  const int xcd = id & 7;
  const int r = id >> 3;
  const int bh = (xcd << 2) | (r & 3);
  const int p = r >> 2;  // 0..15
  const int qiA = 31 - p, qiB = p;

  const size_t base = (size_t)bh * (SEQ * DHEAD);
  const bool causal = (amask[0] != 0);
  const int ntA = causal ? (qiA + 1) : (SEQ / 64);
  const int ntB = causal ? (qiB + 1) : (SEQ / 64);
  const int nt = ntA + ntB;
  const int b = bh >> 4, h = bh & 15;

  int qseg0 = qiA * 64;

  // Q fragments (Q pre-scaled by 0.125*log2e): B-operand, lane col = q.
  bf16x8 qf[2];
  {
    const u16* qp = Qb + base + (size_t)(qseg0 + (w << 4) + l16) * DHEAD + (lg << 3);
    qf[0] = *(const bf16x8*)qp;
    qf[1] = *(const bf16x8*)(qp + 32);
  }

  float mrow = -1e30f, lrow = 0.f;
  f32x4 oacc[4] = {};

  const int vcol = (tid & 7) << 3;
  const int vrow = tid >> 3;
  const int key = (l16 & 7) << 2;  // P-buffer XOR key (function of row only)
  char* prow = (char*)(&Ps[w][0]) + l16 * 128;

  // prologue: stage kv-tile 0
  stage_k(Kb, base, 0, Ks[0], w, lane);
  {
    uint4 va = *(const uint4*)(Vb + base + (size_t)vrow * DHEAD + vcol);
    uint4 vb2 = *(const uint4*)(Vb + base + (size_t)(32 + vrow) * DHEAD + vcol);
    write_vt(Vt[0], va, vb2, tid);
  }
  tile_barrier();

  int cur = 0;
  for (int t = 0; t < nt; ++t) {
    const int j = (t >= ntA) ? (t - ntA) : t;  // kv-tile index within segment
    const u16* Kcur = Ks[cur];
    const u16* Vcur = Vt[cur];
    const bool pre = (t + 1 < nt);
    uint4 vna = {}, vnb = {};
    if (pre) {
      const int jn = (t + 1 >= ntA) ? (t + 1 - ntA) : (t + 1);
      stage_k(Kb, base, jn, Ks[cur ^ 1], w, lane);
      const u16* vsrc = Vb + base + (size_t)jn * 64 * DHEAD;
      vna = *(const uint4*)(vsrc + (size_t)vrow * DHEAD + vcol);
      vnb = *(const uint4*)(vsrc + (size_t)(32 + vrow) * DHEAD + vcol);
    }

    // S^T = K Q^T : sv[nf] rows = kv (nf*16 + lg*4 + i), col = q (l16)
    f32x4 sv[4];
    __builtin_amdgcn_s_setprio(1);
#pragma unroll
    for (int nf = 0; nf < 4; ++nf) {
      const int row = nf * 16 + l16;
      const int sw = (row & 7) << 4;
      bf16x8 kf0 = *(const bf16x8*)((const char*)Kcur + row * 128 + ((lg << 4) ^ sw));
      bf16x8 kf1 = *(const bf16x8*)((const char*)Kcur + row * 128 + ((64 | (lg << 4)) ^ sw));
      f32x4 s = {};
      s = mfma16(kf0, qf[0], s);
      s = mfma16(kf1, qf[1], s);
      sv[nf] = s;
    }
    __builtin_amdgcn_s_setprio(0);

    const bool segEnd = (t == ntA - 1) || (t == nt - 1);
    if (causal && segEnd) {  // diagonal tile: mask kv > q
      const int q = qseg0 + (w << 4) + l16;
#pragma unroll
      for (int nf = 0; nf < 4; ++nf)
#pragma unroll
        for (int i = 0; i < 4; ++i) {
          const int kv = j * 64 + nf * 16 + (lg << 2) + i;
          if (kv > q) sv[nf][i] = -1e30f;
        }
    }

    // tile max: in-lane tree over 16 + 2 shuffles across lg
    float tmax;
    {
      float t0 = fmaxf(fmaxf(sv[0][0], sv[0][1]), fmaxf(sv[0][2], sv[0][3]));
      float t1 = fmaxf(fmaxf(sv[1][0], sv[1][1]), fmaxf(sv[1][2], sv[1][3]));
      float t2 = fmaxf(fmaxf(sv[2][0], sv[2][1]), fmaxf(sv[2][2], sv[2][3]));
      float t3 = fmaxf(fmaxf(sv[3][0], sv[3][1]), fmaxf(sv[3][2], sv[3][3]));
      tmax = fmaxf(fmaxf(t0, t1), fmaxf(t2, t3));
      tmax = fmaxf(tmax, __shfl_xor(tmax, 16));
      tmax = fmaxf(tmax, __shfl_xor(tmax, 32));
    }

    // defer-max (T13, log2 domain)
    if (__any(tmax > mrow + 8.0f)) {
      const float mnew = fmaxf(mrow, tmax);
      const float corr = exp2f(mrow - mnew);
      mrow = mnew;
      lrow *= corr;
#pragma unroll
      for (int df = 0; df < 4; ++df)
#pragma unroll
        for (int i = 0; i < 4; ++i) oacc[df][i] *= corr;
    }

    // P = exp2(S - m): in-lane, pack pairs to u32, store to per-wave LDS
    float psum = 0.f;
#pragma unroll
    for (int nf = 0; nf < 4; ++nf) {
      const float p0 = exp2f(sv[nf][0] - mrow);
      const float p1 = exp2f(sv[nf][1] - mrow);
      const float p2 = exp2f(sv[nf][2] - mrow);
      const float p3 = exp2f(sv[nf][3] - mrow);
      psum += (p0 + p1) + (p2 + p3);
      uint2 pk;
      pk.x = f2b(p0) | ((uint32_t)f2b(p1) << 16);
      pk.y = f2b(p2) | ((uint32_t)f2b(p3) << 16);
      const int word = ((nf << 3) | (lg << 1)) ^ key;
      *(uint2*)(prow + word * 4) = pk;
    }
    psum += __shfl_xor(psum, 16);
    psum += __shfl_xor(psum, 32);
    lrow += psum;

    // reload P as B-operand fragments: P[q=l16][kv = lg*8+e (+32)]
    bf16x8 pa0 = *(const bf16x8*)(prow + ((((lg << 2)) ^ key) << 2));
    bf16x8 pa1 = *(const bf16x8*)(prow + (((16 | (lg << 2)) ^ key) << 2));

    // O^T += V^T P^T : A = V^T rows d, B = P^T cols q
    __builtin_amdgcn_s_setprio(1);
#pragma unroll
    for (int df = 0; df < 4; ++df) {
      const int row = df * 16 + l16;
      const int sw = vswz(row);
      bf16x8 vf0 = *(const bf16x8*)((const char*)Vcur + row * 128 + ((lg << 4) ^ sw));
      bf16x8 vf1 = *(const bf16x8*)((const char*)Vcur + row * 128 + ((64 | (lg << 4)) ^ sw));
      oacc[df] = mfma16(vf0, pa0, oacc[df]);
      oacc[df] = mfma16(vf1, pa1, oacc[df]);
    }
    __builtin_amdgcn_s_setprio(0);

    if (segEnd) {
      // flush this q-tile: lane owns q = qseg0 + w*16 + l16, d = df*16+lg*4+i
      const float inv = 1.0f / lrow;
      const int s = qseg0 + (w << 4) + l16;
      u16* orow = Ob + (size_t)(b * SEQ + s) * DEMB + h * DHEAD;
#pragma unroll
      for (int df = 0; df < 4; ++df) {
        ushort4 o;
        o.x = f2b(oacc[df][0] * inv);
        o.y = f2b(oacc[df][1] * inv);
        o.z = f2b(oacc[df][2] * inv);
        o.w = f2b(oacc[df][3] * inv);
        *(ushort4*)(orow + df * 16 + (lg << 2)) = o;
      }
      if (t != nt - 1) {  // switch to segment B (q-tile qiB)
        qseg0 = qiB * 64;
        mrow = -1e30f;
        lrow = 0.f;
#pragma unroll
        for (int df = 0; df < 4; ++df)
#pragma unroll
          for (int i = 0; i < 4; ++i) oacc[df][i] = 0.f;
        const u16* qp = Qb + base + (size_t)(qseg0 + (w << 4) + l16) * DHEAD + (lg << 3);
        qf[0] = *(const bf16x8*)qp;
        qf[1] = *(const bf16x8*)(qp + 32);
      }
    }

    if (pre) {
      write_vt(Vt[cur ^ 1], vna, vnb, tid);
      tile_barrier();
    }
    cur ^= 1;
  }
}

extern "C" void kernel_launch(void* const* d_in, const int* in_sizes, int n_in,
                              void* d_out, int out_size, void* d_ws, size_t ws_size,
                              hipStream_t stream) {
  const float* x = (const float*)d_in[0];
  const float* w_in = (const float*)d_in[1];
  const float* b_in = (const float*)d_in[2];
  const float* w_out = (const float*)d_in[3];
  const float* b_out = (const float*)d_in[4];
  const int* amask = (const int*)d_in[5];
  float* out = (float*)d_out;

  u16* xb = (u16*)d_ws;
  u16* wib = xb + (size_t)MROWS * DEMB;
  u16* wob = wib + (size_t)3 * DEMB * DEMB;
  u16* Qb = wob + (size_t)DEMB * DEMB;
  u16* Kb = Qb + (size_t)MROWS * DEMB;
  u16* Vb = Kb + (size_t)MROWS * DEMB;
  u16* Ab = xb;  // attn output reuses x-bf16 region

  cvt3_f32_bf16<<<2048, 256, 0, stream>>>(x, MROWS * DEMB, w_in, 3 * DEMB * DEMB,
                                          w_out, DEMB * DEMB, xb, wib, wob);

  gemm_nt<0><<<dim3(24, 32), 256, 0, stream>>>(xb, wib, b_in, DEMB, 3 * DEMB,
                                               Qb, Kb, Vb, nullptr);
  attn_fwd<<<512, 256, 0, stream>>>(Qb, Kb, Vb, Ab, amask);
  gemm_nt<1><<<dim3(8, 32), 256, 0, stream>>>(Ab, wob, b_out, DEMB, DEMB,
                                              nullptr, nullptr, nullptr, out);
}

// Round 7
// 111.795 us; speedup vs baseline: 2.6058x; 1.0608x over previous
//
#include <hip/hip_runtime.h>
#include <stdint.h>

#define DEMB 1024
#define NHEAD 16
#define DHEAD 64
#define SEQ 2048
#define MROWS 4096  // B*S

typedef __bf16 bf16x8 __attribute__((ext_vector_type(8)));
typedef float f32x4 __attribute__((ext_vector_type(4)));
typedef unsigned short u16;

#define LOG2E 1.44269504088896340736f

__device__ __forceinline__ u16 f2b(float f) {
  return __builtin_bit_cast(u16, (__bf16)f);  // RNE, compiler can pack pairs
}
__device__ __forceinline__ uint32_t pk2(float a, float b) {
  return (uint32_t)f2b(a) | ((uint32_t)f2b(b) << 16);
}

__device__ __forceinline__ f32x4 mfma16(bf16x8 a, bf16x8 b, f32x4 c) {
  return __builtin_amdgcn_mfma_f32_16x16x32_bf16(a, b, c, 0, 0, 0);
}

__device__ __forceinline__ void gload_lds16(const void* g, void* l) {
  __builtin_amdgcn_global_load_lds(
      (__attribute__((address_space(1))) unsigned int*)(g),
      (__attribute__((address_space(3))) unsigned int*)(l), 16, 0, 0);
}

__device__ __forceinline__ void tile_barrier() {
  __builtin_amdgcn_sched_barrier(0);
  asm volatile("s_waitcnt vmcnt(0) lgkmcnt(0)" ::: "memory");
  __builtin_amdgcn_s_barrier();
  __builtin_amdgcn_sched_barrier(0);
}

// fused fp32->bf16 convert of three regions (sizes all multiples of 4)
__global__ void cvt3_f32_bf16(const float* __restrict__ a, int na,
                              const float* __restrict__ b, int nb,
                              const float* __restrict__ c, int nc,
                              u16* __restrict__ da, u16* __restrict__ db,
                              u16* __restrict__ dc) {
  const int total = (na + nb + nc) >> 2;
  const int stride = gridDim.x * blockDim.x;
  for (int t = blockIdx.x * blockDim.x + threadIdx.x; t < total; t += stride) {
    int i = t << 2;
    const float* s;
    u16* d;
    if (i < na) {
      s = a + i; d = da + i;
    } else if (i < na + nb) {
      s = b + (i - na); d = db + (i - na);
    } else {
      s = c + (i - na - nb); d = dc + (i - na - nb);
    }
    float4 f = *(const float4*)s;
    ushort4 o;
    o.x = f2b(f.x); o.y = f2b(f.y); o.z = f2b(f.z); o.w = f2b(f.w);
    *(ushort4*)d = o;
  }
}

// NT GEMM (unchanged this round): C[m,n] = sum_k A[m,k]*B[n,k] (+bias[n]).
template <int EPI>
__global__ __launch_bounds__(256, 2) void gemm_nt(
    const u16* __restrict__ A, const u16* __restrict__ Bw,
    const float* __restrict__ bias, int K, int N,
    u16* __restrict__ q_out, u16* __restrict__ k_out, u16* __restrict__ v_out,
    float* __restrict__ f_out) {
  __shared__ __align__(16) u16 As[128 * 64];
  __shared__ __align__(16) u16 Bs[128 * 64];
  const int tid = threadIdx.x;
  const int w = tid >> 6;
  const int lane = tid & 63;
  const int wm = w >> 1, wn = w & 1;
  const int m0 = blockIdx.y * 128, n0 = blockIdx.x * 128;
  const int l16 = lane & 15, lg = lane >> 4;
  const int st_row = lane >> 3, st_slot = lane & 7;

  f32x4 acc[4][4] = {};

  for (int k0 = 0; k0 < K; k0 += 64) {
#pragma unroll
    for (int i = 0; i < 4; ++i) {
      const int chunk = (w << 2) | i;
      const int row = (chunk << 3) | st_row;
      const int scol = (st_slot ^ (row & 7)) << 3;
      gload_lds16(A + (size_t)(m0 + row) * K + k0 + scol, (char*)As + (chunk << 10));
      gload_lds16(Bw + (size_t)(n0 + row) * K + k0 + scol, (char*)Bs + (chunk << 10));
    }
    __syncthreads();
#pragma unroll
    for (int ks = 0; ks < 2; ++ks) {
      bf16x8 af[4], bfr[4];
#pragma unroll
      for (int mi = 0; mi < 4; ++mi) {
        const int row = wm * 64 + mi * 16 + l16;
        const int cb = ((ks << 6) | (lg << 4)) ^ ((row & 7) << 4);
        af[mi] = *(const bf16x8*)((const char*)As + row * 128 + cb);
      }
#pragma unroll
      for (int ni = 0; ni < 4; ++ni) {
        const int row = wn * 64 + ni * 16 + l16;
        const int cb = ((ks << 6) | (lg << 4)) ^ ((row & 7) << 4);
        bfr[ni] = *(const bf16x8*)((const char*)Bs + row * 128 + cb);
      }
#pragma unroll
      for (int mi = 0; mi < 4; ++mi)
#pragma unroll
        for (int ni = 0; ni < 4; ++ni)
          acc[mi][ni] = mfma16(af[mi], bfr[ni], acc[mi][ni]);
    }
    __syncthreads();
  }

#pragma unroll
  for (int ni = 0; ni < 4; ++ni) {
    const int n = n0 + wn * 64 + ni * 16 + l16;
    const float bv = bias[n];
    if (EPI == 0) {
      const int part = n >> 10;
      const int hh = (n >> 6) & 15;
      const int dh = n & 63;
      const float scl = (part == 0) ? (0.125f * LOG2E) : 1.0f;
      u16* dst = (part == 0) ? q_out : (part == 1) ? k_out : v_out;
#pragma unroll
      for (int mi = 0; mi < 4; ++mi) {
#pragma unroll
        for (int i = 0; i < 4; ++i) {
          const int m = m0 + wm * 64 + mi * 16 + (lg << 2) + i;
          const int bq = m >> 11, s = m & 2047;
          dst[((size_t)((bq << 4) | hh) * SEQ + s) * DHEAD + dh] = f2b((acc[mi][ni][i] + bv) * scl);
        }
      }
    } else {
#pragma unroll
      for (int mi = 0; mi < 4; ++mi)
#pragma unroll
        for (int i = 0; i < 4; ++i) {
          const int m = m0 + wm * 64 + mi * 16 + (lg << 2) + i;
          f_out[(size_t)m * N + n] = acc[mi][ni][i] + bv;
        }
    }
  }
}

// ---- attention (KVBLK=128, 256B LDS rows, swz4, conflict-free b128) ----
__device__ __forceinline__ int swz4(int r) { return (r ^ (r >> 3)) & 15; }

// K tile: 128 kv x 64 d packed as LDS [64 rows][256B]; row r2 holds kv {2r2, 2r2+1}.
// 16B slot s' at row r2 stores unswizzled slot s = s'^swz4(r2):
//   kv = 2*r2 + (s>>3), d = (s&7)*8 .. +7
__device__ __forceinline__ void stage_k(const u16* __restrict__ Kb, size_t base,
                                        int jt, u16* Ks, int w, int lane) {
#pragma unroll
  for (int i = 0; i < 4; ++i) {
    const int g = (w << 2) | i;               // 0..15: 1KB chunk id
    const int row = (g << 2) | (lane >> 4);   // LDS row 0..63
    const int shat = (lane & 15) ^ swz4(row); // unswizzled slot
    const int kv = (row << 1) | (shat >> 3);
    const int del = (shat & 7) << 3;
    gload_lds16(Kb + base + (size_t)(jt * 128 + kv) * DHEAD + del,
                (char*)Ks + (g << 10));
  }
}

// V transpose into Vt[d=64][kv=128] (256B rows), swz4 at 16B granularity.
__device__ __forceinline__ void write_vt(u16* Vt, const uint4* v, int tid) {
  const int c0 = (tid & 7) << 3;
  const int vrb = tid >> 3;
#pragma unroll
  for (int k = 0; k < 4; ++k) {
    const int vr = vrb + (k << 5);
    const u16* pv = (const u16*)&v[k];
#pragma unroll
    for (int e = 0; e < 8; ++e) {
      const int rt = c0 + e;
      *(u16*)((char*)Vt + rt * 256 + ((vr << 1) ^ (swz4(rt) << 4))) = pv[e];
    }
  }
}

// Swapped-operand flash attention. QBLK=64 (4 waves x 16 q), KVBLK=128, dbuf.
// Pair (31-p, p): uniform 17 causal kv-iterations per block; 512 blocks.
__global__ __launch_bounds__(256, 2) void attn_fwd(
    const u16* __restrict__ Qb, const u16* __restrict__ Kb,
    const u16* __restrict__ Vb, u16* __restrict__ Ob,
    const int* __restrict__ amask) {
  __shared__ __align__(16) u16 Ks[2][64 * 128];
  __shared__ __align__(16) u16 Vt[2][64 * 128];
  __shared__ __align__(16) uint32_t Ps[4][1024];  // per-wave 16q x 128kv bf16
  const int tid = threadIdx.x;
  const int w = tid >> 6, lane = tid & 63;
  const int l16 = lane & 15, lg = lane >> 4;

  const int id = blockIdx.x;
  const int xcd = id & 7;
  const int r = id >> 3;
  const int bh = (xcd << 2) | (r & 3);
  const int p = r >> 2;  // 0..15
  const int qiA = 31 - p, qiB = p;

  const size_t base = (size_t)bh * (SEQ * DHEAD);
  const bool causal = (amask[0] != 0);
  const int ntA = causal ? ((qiA >> 1) + 1) : (SEQ / 128);
  const int ntB = causal ? ((qiB >> 1) + 1) : (SEQ / 128);
  const int nt = ntA + ntB;
  const int b = bh >> 4, h = bh & 15;

  int qseg0 = qiA * 64;

  // Q fragments (pre-scaled by 0.125*log2e): B-operand, lane col = q = l16.
  bf16x8 qf[2];
  {
    const u16* qp = Qb + base + (size_t)(qseg0 + (w << 4) + l16) * DHEAD + (lg << 3);
    qf[0] = *(const bf16x8*)qp;
    qf[1] = *(const bf16x8*)(qp + 32);
  }

  float mrow = -1e30f, lrow = 0.f;
  f32x4 oacc[4] = {};

  const int vcol = (tid & 7) << 3;
  const int vrow = tid >> 3;
  const int key = (l16 & 7) << 2;
  char* prow = (char*)(&Ps[w][0]) + l16 * 256;

  // prologue: stage kv-tile 0
  stage_k(Kb, base, 0, Ks[0], w, lane);
  {
    uint4 v[4];
#pragma unroll
    for (int k = 0; k < 4; ++k)
      v[k] = *(const uint4*)(Vb + base + (size_t)(vrow + (k << 5)) * DHEAD + vcol);
    write_vt(Vt[0], v, tid);
  }
  tile_barrier();

  int cur = 0;
  for (int t = 0; t < nt; ++t) {
    const int j = (t >= ntA) ? (t - ntA) : t;
    const u16* Kcur = Ks[cur];
    const u16* Vcur = Vt[cur];
    const bool pre = (t + 1 < nt);
    uint4 vn[4] = {};
    if (pre) {
      const int jn = (t + 1 >= ntA) ? (t + 1 - ntA) : (t + 1);
      stage_k(Kb, base, jn, Ks[cur ^ 1], w, lane);
      const u16* vsrc = Vb + base + (size_t)jn * 128 * DHEAD;
#pragma unroll
      for (int k = 0; k < 4; ++k)
        vn[k] = *(const uint4*)(vsrc + (size_t)(vrow + (k << 5)) * DHEAD + vcol);
    }

    // S^T = K Q^T : sv[nf], kv = nf*16 + lg*4 + i, col q = l16
    f32x4 sv[8];
    __builtin_amdgcn_s_setprio(1);
#pragma unroll
    for (int nf = 0; nf < 8; ++nf) {
      const int row2 = (nf << 3) | (l16 >> 1);     // LDS row (kv>>1)
      const int sz = swz4(row2);
      const int s0 = ((l16 & 1) << 3) | lg;
      bf16x8 kf0 = *(const bf16x8*)((const char*)Kcur + row2 * 256 + ((s0 ^ sz) << 4));
      bf16x8 kf1 = *(const bf16x8*)((const char*)Kcur + row2 * 256 + (((s0 | 4) ^ sz) << 4));
      f32x4 s = {};
      s = mfma16(kf0, qf[0], s);
      s = mfma16(kf1, qf[1], s);
      sv[nf] = s;
    }
    __builtin_amdgcn_s_setprio(0);

    const bool segEnd = (t == ntA - 1) || (t == nt - 1);
    if (causal && segEnd) {  // diagonal tile: mask kv > q
      const int q = qseg0 + (w << 4) + l16;
#pragma unroll
      for (int nf = 0; nf < 8; ++nf)
#pragma unroll
        for (int i = 0; i < 4; ++i) {
          const int kv = j * 128 + (nf << 4) + (lg << 2) + i;
          if (kv > q) sv[nf][i] = -1e30f;
        }
    }

    // tile max: pairwise tree in-lane + 2 shuffles across lg
    float tmax;
    {
      f32x4 m01, m23, m45, m67, ma, mb, mt;
#pragma unroll
      for (int i = 0; i < 4; ++i) {
        m01[i] = fmaxf(sv[0][i], sv[1][i]);
        m23[i] = fmaxf(sv[2][i], sv[3][i]);
        m45[i] = fmaxf(sv[4][i], sv[5][i]);
        m67[i] = fmaxf(sv[6][i], sv[7][i]);
        ma[i] = fmaxf(m01[i], m23[i]);
        mb[i] = fmaxf(m45[i], m67[i]);
        mt[i] = fmaxf(ma[i], mb[i]);
      }
      tmax = fmaxf(fmaxf(mt[0], mt[1]), fmaxf(mt[2], mt[3]));
      tmax = fmaxf(tmax, __shfl_xor(tmax, 16));
      tmax = fmaxf(tmax, __shfl_xor(tmax, 32));
    }

    // defer-max (T13, log2 domain)
    if (__any(tmax > mrow + 8.0f)) {
      const float mnew = fmaxf(mrow, tmax);
      const float corr = __builtin_amdgcn_exp2f(mrow - mnew);
      mrow = mnew;
      lrow *= corr;
#pragma unroll
      for (int df = 0; df < 4; ++df)
#pragma unroll
        for (int i = 0; i < 4; ++i) oacc[df][i] *= corr;
    }

    // P = exp2(S - m): pack to bf16 pairs, store per-wave LDS
    float ps0 = 0.f, ps1 = 0.f;
#pragma unroll
    for (int nf = 0; nf < 8; ++nf) {
      const float p0 = __builtin_amdgcn_exp2f(sv[nf][0] - mrow);
      const float p1 = __builtin_amdgcn_exp2f(sv[nf][1] - mrow);
      const float p2 = __builtin_amdgcn_exp2f(sv[nf][2] - mrow);
      const float p3 = __builtin_amdgcn_exp2f(sv[nf][3] - mrow);
      ps0 += p0 + p1;
      ps1 += p2 + p3;
      uint2 pkv;
      pkv.x = pk2(p0, p1);
      pkv.y = pk2(p2, p3);
      const int word = ((nf << 3) | (lg << 1)) ^ key;
      *(uint2*)(prow + word * 4) = pkv;
    }
    float psum = ps0 + ps1;
    psum += __shfl_xor(psum, 16);
    psum += __shfl_xor(psum, 32);
    lrow += psum;

    // reload P as B-operand frags: pa[s], kv = 32s + lg*8 + e
    bf16x8 pa[4];
#pragma unroll
    for (int s = 0; s < 4; ++s)
      pa[s] = *(const bf16x8*)(prow + ((((s << 4) | (lg << 2)) ^ key) << 2));

    // O^T += V^T P^T
    __builtin_amdgcn_s_setprio(1);
#pragma unroll
    for (int df = 0; df < 4; ++df) {
      const int row = (df << 4) + l16;
      const int sz = swz4(row) << 4;
#pragma unroll
      for (int s = 0; s < 4; ++s) {
        bf16x8 vf = *(const bf16x8*)((const char*)Vcur + row * 256 + (((s << 6) | (lg << 4)) ^ sz));
        oacc[df] = mfma16(vf, pa[s], oacc[df]);
      }
    }
    __builtin_amdgcn_s_setprio(0);

    if (segEnd) {
      const float inv = 1.0f / lrow;
      const int s = qseg0 + (w << 4) + l16;
      u16* orow = Ob + (size_t)(b * SEQ + s) * DEMB + h * DHEAD;
#pragma unroll
      for (int df = 0; df < 4; ++df) {
        ushort4 o;
        o.x = f2b(oacc[df][0] * inv);
        o.y = f2b(oacc[df][1] * inv);
        o.z = f2b(oacc[df][2] * inv);
        o.w = f2b(oacc[df][3] * inv);
        *(ushort4*)(orow + (df << 4) + (lg << 2)) = o;
      }
      if (t != nt - 1) {  // switch to segment B
        qseg0 = qiB * 64;
        mrow = -1e30f;
        lrow = 0.f;
#pragma unroll
        for (int df = 0; df < 4; ++df)
#pragma unroll
          for (int i = 0; i < 4; ++i) oacc[df][i] = 0.f;
        const u16* qp = Qb + base + (size_t)(qseg0 + (w << 4) + l16) * DHEAD + (lg << 3);
        qf[0] = *(const bf16x8*)qp;
        qf[1] = *(const bf16x8*)(qp + 32);
      }
    }

    if (pre) {
      write_vt(Vt[cur ^ 1], vn, tid);
      tile_barrier();
    }
    cur ^= 1;
  }
}

extern "C" void kernel_launch(void* const* d_in, const int* in_sizes, int n_in,
                              void* d_out, int out_size, void* d_ws, size_t ws_size,
                              hipStream_t stream) {
  const float* x = (const float*)d_in[0];
  const float* w_in = (const float*)d_in[1];
  const float* b_in = (const float*)d_in[2];
  const float* w_out = (const float*)d_in[3];
  const float* b_out = (const float*)d_in[4];
  const int* amask = (const int*)d_in[5];
  float* out = (float*)d_out;

  u16* xb = (u16*)d_ws;
  u16* wib = xb + (size_t)MROWS * DEMB;
  u16* wob = wib + (size_t)3 * DEMB * DEMB;
  u16* Qb = wob + (size_t)DEMB * DEMB;
  u16* Kb = Qb + (size_t)MROWS * DEMB;
  u16* Vb = Kb + (size_t)MROWS * DEMB;
  u16* Ab = xb;  // attn output reuses x-bf16 region

  cvt3_f32_bf16<<<2048, 256, 0, stream>>>(x, MROWS * DEMB, w_in, 3 * DEMB * DEMB,
                                          w_out, DEMB * DEMB, xb, wib, wob);

  gemm_nt<0><<<dim3(24, 32), 256, 0, stream>>>(xb, wib, b_in, DEMB, 3 * DEMB,
                                               Qb, Kb, Vb, nullptr);
  attn_fwd<<<512, 256, 0, stream>>>(Qb, Kb, Vb, Ab, amask);
  gemm_nt<1><<<dim3(8, 32), 256, 0, stream>>>(Ab, wob, b_out, DEMB, DEMB,
                                              nullptr, nullptr, nullptr, out);
}

// Round 8
// 102.213 us; speedup vs baseline: 2.8501x; 1.0938x over previous
//
#include <hip/hip_runtime.h>
#include <stdint.h>

#define DEMB 1024
#define NHEAD 16
#define DHEAD 64
#define SEQ 2048
#define MROWS 4096  // B*S

typedef __bf16 bf16x8 __attribute__((ext_vector_type(8)));
typedef float f32x4 __attribute__((ext_vector_type(4)));
typedef unsigned short u16;

#define LOG2E 1.44269504088896340736f

__device__ __forceinline__ u16 f2b(float f) {
  return __builtin_bit_cast(u16, (__bf16)f);  // RNE, compiler can pack pairs
}
__device__ __forceinline__ uint32_t pk2(float a, float b) {
  return (uint32_t)f2b(a) | ((uint32_t)f2b(b) << 16);
}

__device__ __forceinline__ f32x4 mfma16(bf16x8 a, bf16x8 b, f32x4 c) {
  return __builtin_amdgcn_mfma_f32_16x16x32_bf16(a, b, c, 0, 0, 0);
}

__device__ __forceinline__ void gload_lds16(const void* g, void* l) {
  __builtin_amdgcn_global_load_lds(
      (__attribute__((address_space(1))) unsigned int*)(g),
      (__attribute__((address_space(3))) unsigned int*)(l), 16, 0, 0);
}

__device__ __forceinline__ void tile_barrier() {
  __builtin_amdgcn_sched_barrier(0);
  asm volatile("s_waitcnt vmcnt(0) lgkmcnt(0)" ::: "memory");
  __builtin_amdgcn_s_barrier();
  __builtin_amdgcn_sched_barrier(0);
}

// fused fp32->bf16 convert of three regions (sizes all multiples of 4)
__global__ void cvt3_f32_bf16(const float* __restrict__ a, int na,
                              const float* __restrict__ b, int nb,
                              const float* __restrict__ c, int nc,
                              u16* __restrict__ da, u16* __restrict__ db,
                              u16* __restrict__ dc) {
  const int total = (na + nb + nc) >> 2;
  const int stride = gridDim.x * blockDim.x;
  for (int t = blockIdx.x * blockDim.x + threadIdx.x; t < total; t += stride) {
    int i = t << 2;
    const float* s;
    u16* d;
    if (i < na) {
      s = a + i; d = da + i;
    } else if (i < na + nb) {
      s = b + (i - na); d = db + (i - na);
    } else {
      s = c + (i - na - nb); d = dc + (i - na - nb);
    }
    float4 f = *(const float4*)s;
    ushort4 o;
    o.x = f2b(f.x); o.y = f2b(f.y); o.z = f2b(f.z); o.w = f2b(f.w);
    *(ushort4*)d = o;
  }
}

// NT GEMM: C[m,n] = sum_k A[m,k]*B[n,k] (+bias[n]).
// EPI==0: scatter Q,K to [B,H,S,Dh] bf16 (Q pre-scaled by 0.125*log2e);
//         V is written TRANSPOSED: Vt[bh][d][s] (ushort4 of 4 consecutive s).
// EPI==1: write fp32 C[m*N+n].
template <int EPI>
__global__ __launch_bounds__(256, 2) void gemm_nt(
    const u16* __restrict__ A, const u16* __restrict__ Bw,
    const float* __restrict__ bias, int K, int N,
    u16* __restrict__ q_out, u16* __restrict__ k_out, u16* __restrict__ v_out,
    float* __restrict__ f_out) {
  __shared__ __align__(16) u16 As[128 * 64];
  __shared__ __align__(16) u16 Bs[128 * 64];
  const int tid = threadIdx.x;
  const int w = tid >> 6;
  const int lane = tid & 63;
  const int wm = w >> 1, wn = w & 1;
  const int m0 = blockIdx.y * 128, n0 = blockIdx.x * 128;
  const int l16 = lane & 15, lg = lane >> 4;
  const int st_row = lane >> 3, st_slot = lane & 7;

  f32x4 acc[4][4] = {};

  for (int k0 = 0; k0 < K; k0 += 64) {
#pragma unroll
    for (int i = 0; i < 4; ++i) {
      const int chunk = (w << 2) | i;
      const int row = (chunk << 3) | st_row;
      const int scol = (st_slot ^ (row & 7)) << 3;
      gload_lds16(A + (size_t)(m0 + row) * K + k0 + scol, (char*)As + (chunk << 10));
      gload_lds16(Bw + (size_t)(n0 + row) * K + k0 + scol, (char*)Bs + (chunk << 10));
    }
    __syncthreads();
#pragma unroll
    for (int ks = 0; ks < 2; ++ks) {
      bf16x8 af[4], bfr[4];
#pragma unroll
      for (int mi = 0; mi < 4; ++mi) {
        const int row = wm * 64 + mi * 16 + l16;
        const int cb = ((ks << 6) | (lg << 4)) ^ ((row & 7) << 4);
        af[mi] = *(const bf16x8*)((const char*)As + row * 128 + cb);
      }
#pragma unroll
      for (int ni = 0; ni < 4; ++ni) {
        const int row = wn * 64 + ni * 16 + l16;
        const int cb = ((ks << 6) | (lg << 4)) ^ ((row & 7) << 4);
        bfr[ni] = *(const bf16x8*)((const char*)Bs + row * 128 + cb);
      }
#pragma unroll
      for (int mi = 0; mi < 4; ++mi)
#pragma unroll
        for (int ni = 0; ni < 4; ++ni)
          acc[mi][ni] = mfma16(af[mi], bfr[ni], acc[mi][ni]);
    }
    __syncthreads();
  }

#pragma unroll
  for (int ni = 0; ni < 4; ++ni) {
    const int n = n0 + wn * 64 + ni * 16 + l16;
    const float bv = bias[n];
    if (EPI == 0) {
      const int part = n >> 10;
      const int hh = (n >> 6) & 15;
      const int dh = n & 63;
      if (part == 2) {
        // V^T: [bh][d][s], 4 consecutive s per ushort4
#pragma unroll
        for (int mi = 0; mi < 4; ++mi) {
          const int mbase = m0 + wm * 64 + mi * 16 + (lg << 2);
          const int bq = mbase >> 11, s0 = mbase & 2047;
          ushort4 o;
          o.x = f2b(acc[mi][ni][0] + bv);
          o.y = f2b(acc[mi][ni][1] + bv);
          o.z = f2b(acc[mi][ni][2] + bv);
          o.w = f2b(acc[mi][ni][3] + bv);
          *(ushort4*)(v_out + ((size_t)(((bq << 4) | hh) * 64 + dh)) * SEQ + s0) = o;
        }
      } else {
        const float scl = (part == 0) ? (0.125f * LOG2E) : 1.0f;
        u16* dst = (part == 0) ? q_out : k_out;
#pragma unroll
        for (int mi = 0; mi < 4; ++mi) {
#pragma unroll
          for (int i = 0; i < 4; ++i) {
            const int m = m0 + wm * 64 + mi * 16 + (lg << 2) + i;
            const int bq = m >> 11, s = m & 2047;
            dst[((size_t)((bq << 4) | hh) * SEQ + s) * DHEAD + dh] = f2b((acc[mi][ni][i] + bv) * scl);
          }
        }
      }
    } else {
#pragma unroll
      for (int mi = 0; mi < 4; ++mi)
#pragma unroll
        for (int i = 0; i < 4; ++i) {
          const int m = m0 + wm * 64 + mi * 16 + (lg << 2) + i;
          f_out[(size_t)m * N + n] = acc[mi][ni][i] + bv;
        }
    }
  }
}

// ---- attention (KVBLK=128, 256B LDS rows, swz4, all-gload_lds staging) ----
__device__ __forceinline__ int swz4(int r) { return (r ^ (r >> 3)) & 15; }

// K tile: 128 kv x 64 d packed as LDS [64 rows][256B]; row r2 holds kv {2r2, 2r2+1}.
// 16B slot s' at row r2 stores unswizzled slot s = s'^swz4(r2):
//   kv = 2*r2 + (s>>3), d = (s&7)*8 .. +7
__device__ __forceinline__ void stage_k(const u16* __restrict__ Kb, size_t base,
                                        int jt, u16* Ks, int w, int lane) {
#pragma unroll
  for (int i = 0; i < 4; ++i) {
    const int g = (w << 2) | i;               // 0..15: 1KB chunk id
    const int row = (g << 2) | (lane >> 4);   // LDS row 0..63
    const int shat = (lane & 15) ^ swz4(row); // unswizzled slot
    const int kv = (row << 1) | (shat >> 3);
    const int del = (shat & 7) << 3;
    gload_lds16(Kb + base + (size_t)(jt * 128 + kv) * DHEAD + del,
                (char*)Ks + (g << 10));
  }
}

// V tile from pre-transposed global Vt[bh][d][s]: LDS [64 d-rows][256B=128 kv],
// same swz4 slot swizzle. Slot s covers kv = jt*128 + s*8 .. +7 (contiguous!).
__device__ __forceinline__ void stage_v(const u16* __restrict__ VTg, size_t base,
                                        int jt, u16* Vs, int w, int lane) {
#pragma unroll
  for (int i = 0; i < 4; ++i) {
    const int g = (w << 2) | i;
    const int row = (g << 2) | (lane >> 4);   // d row 0..63
    const int shat = (lane & 15) ^ swz4(row);
    gload_lds16(VTg + base + (size_t)row * SEQ + jt * 128 + (shat << 3),
                (char*)Vs + (g << 10));
  }
}

// Swapped-operand flash attention. QBLK=64 (4 waves x 16 q), KVBLK=128, dbuf.
// Pair (31-p, p): uniform 17 causal kv-iterations per block; 512 blocks.
__global__ __launch_bounds__(256, 2) void attn_fwd(
    const u16* __restrict__ Qb, const u16* __restrict__ Kb,
    const u16* __restrict__ VTg, u16* __restrict__ Ob,
    const int* __restrict__ amask) {
  __shared__ __align__(16) u16 Ks[2][64 * 128];
  __shared__ __align__(16) u16 Vt[2][64 * 128];
  __shared__ __align__(16) uint32_t Ps[4][1024];  // per-wave 16q x 128kv bf16
  const int tid = threadIdx.x;
  const int w = tid >> 6, lane = tid & 63;
  const int l16 = lane & 15, lg = lane >> 4;

  const int id = blockIdx.x;
  const int xcd = id & 7;
  const int r = id >> 3;
  const int bh = (xcd << 2) | (r & 3);
  const int p = r >> 2;  // 0..15
  const int qiA = 31 - p, qiB = p;

  const size_t base = (size_t)bh * (SEQ * DHEAD);  // also = bh*64*SEQ for V^T
  const bool causal = (amask[0] != 0);
  const int ntA = causal ? ((qiA >> 1) + 1) : (SEQ / 128);
  const int ntB = causal ? ((qiB >> 1) + 1) : (SEQ / 128);
  const int nt = ntA + ntB;
  const int b = bh >> 4, h = bh & 15;

  int qseg0 = qiA * 64;

  // Q fragments (pre-scaled by 0.125*log2e): B-operand, lane col = q = l16.
  bf16x8 qf[2];
  {
    const u16* qp = Qb + base + (size_t)(qseg0 + (w << 4) + l16) * DHEAD + (lg << 3);
    qf[0] = *(const bf16x8*)qp;
    qf[1] = *(const bf16x8*)(qp + 32);
  }

  float mrow = -1e30f, lrow = 0.f;
  f32x4 oacc[4] = {};

  const int key = (l16 & 7) << 2;
  char* prow = (char*)(&Ps[w][0]) + l16 * 256;

  // prologue: stage kv-tile 0
  stage_k(Kb, base, 0, Ks[0], w, lane);
  stage_v(VTg, base, 0, Vt[0], w, lane);
  tile_barrier();

  int cur = 0;
  for (int t = 0; t < nt; ++t) {
    const int j = (t >= ntA) ? (t - ntA) : t;
    const u16* Kcur = Ks[cur];
    const u16* Vcur = Vt[cur];
    const bool pre = (t + 1 < nt);
    if (pre) {
      const int jn = (t + 1 >= ntA) ? (t + 1 - ntA) : (t + 1);
      stage_k(Kb, base, jn, Ks[cur ^ 1], w, lane);
      stage_v(VTg, base, jn, Vt[cur ^ 1], w, lane);
    }

    // S^T = K Q^T : sv[nf], kv = nf*16 + lg*4 + i, col q = l16
    f32x4 sv[8];
    __builtin_amdgcn_s_setprio(1);
#pragma unroll
    for (int nf = 0; nf < 8; ++nf) {
      const int row2 = (nf << 3) | (l16 >> 1);     // LDS row (kv>>1)
      const int sz = swz4(row2);
      const int s0 = ((l16 & 1) << 3) | lg;
      bf16x8 kf0 = *(const bf16x8*)((const char*)Kcur + row2 * 256 + ((s0 ^ sz) << 4));
      bf16x8 kf1 = *(const bf16x8*)((const char*)Kcur + row2 * 256 + (((s0 | 4) ^ sz) << 4));
      f32x4 s = {};
      s = mfma16(kf0, qf[0], s);
      s = mfma16(kf1, qf[1], s);
      sv[nf] = s;
    }
    __builtin_amdgcn_s_setprio(0);

    const bool segEnd = (t == ntA - 1) || (t == nt - 1);
    if (causal && segEnd) {  // diagonal tile: mask kv > q
      const int q = qseg0 + (w << 4) + l16;
#pragma unroll
      for (int nf = 0; nf < 8; ++nf)
#pragma unroll
        for (int i = 0; i < 4; ++i) {
          const int kv = j * 128 + (nf << 4) + (lg << 2) + i;
          if (kv > q) sv[nf][i] = -1e30f;
        }
    }

    // tile max: pairwise tree in-lane + 2 shuffles across lg
    float tmax;
    {
      f32x4 m01, m23, m45, m67, ma, mb, mt;
#pragma unroll
      for (int i = 0; i < 4; ++i) {
        m01[i] = fmaxf(sv[0][i], sv[1][i]);
        m23[i] = fmaxf(sv[2][i], sv[3][i]);
        m45[i] = fmaxf(sv[4][i], sv[5][i]);
        m67[i] = fmaxf(sv[6][i], sv[7][i]);
        ma[i] = fmaxf(m01[i], m23[i]);
        mb[i] = fmaxf(m45[i], m67[i]);
        mt[i] = fmaxf(ma[i], mb[i]);
      }
      tmax = fmaxf(fmaxf(mt[0], mt[1]), fmaxf(mt[2], mt[3]));
      tmax = fmaxf(tmax, __shfl_xor(tmax, 16));
      tmax = fmaxf(tmax, __shfl_xor(tmax, 32));
    }

    // defer-max (T13, log2 domain)
    if (__any(tmax > mrow + 8.0f)) {
      const float mnew = fmaxf(mrow, tmax);
      const float corr = __builtin_amdgcn_exp2f(mrow - mnew);
      mrow = mnew;
      lrow *= corr;
#pragma unroll
      for (int df = 0; df < 4; ++df)
#pragma unroll
        for (int i = 0; i < 4; ++i) oacc[df][i] *= corr;
    }

    // P = exp2(S - m): pack to bf16 pairs, store per-wave LDS
    float ps0 = 0.f, ps1 = 0.f;
#pragma unroll
    for (int nf = 0; nf < 8; ++nf) {
      const float p0 = __builtin_amdgcn_exp2f(sv[nf][0] - mrow);
      const float p1 = __builtin_amdgcn_exp2f(sv[nf][1] - mrow);
      const float p2 = __builtin_amdgcn_exp2f(sv[nf][2] - mrow);
      const float p3 = __builtin_amdgcn_exp2f(sv[nf][3] - mrow);
      ps0 += p0 + p1;
      ps1 += p2 + p3;
      uint2 pkv;
      pkv.x = pk2(p0, p1);
      pkv.y = pk2(p2, p3);
      const int word = ((nf << 3) | (lg << 1)) ^ key;
      *(uint2*)(prow + word * 4) = pkv;
    }
    float psum = ps0 + ps1;
    psum += __shfl_xor(psum, 16);
    psum += __shfl_xor(psum, 32);
    lrow += psum;

    // reload P as B-operand frags: pa[s], kv = 32s + lg*8 + e
    bf16x8 pa[4];
#pragma unroll
    for (int s = 0; s < 4; ++s)
      pa[s] = *(const bf16x8*)(prow + ((((s << 4) | (lg << 2)) ^ key) << 2));

    // O^T += V^T P^T
    __builtin_amdgcn_s_setprio(1);
#pragma unroll
    for (int df = 0; df < 4; ++df) {
      const int row = (df << 4) + l16;
      const int sz = swz4(row) << 4;
#pragma unroll
      for (int s = 0; s < 4; ++s) {
        bf16x8 vf = *(const bf16x8*)((const char*)Vcur + row * 256 + (((s << 6) | (lg << 4)) ^ sz));
        oacc[df] = mfma16(vf, pa[s], oacc[df]);
      }
    }
    __builtin_amdgcn_s_setprio(0);

    if (segEnd) {
      const float inv = 1.0f / lrow;
      const int s = qseg0 + (w << 4) + l16;
      u16* orow = Ob + (size_t)(b * SEQ + s) * DEMB + h * DHEAD;
#pragma unroll
      for (int df = 0; df < 4; ++df) {
        ushort4 o;
        o.x = f2b(oacc[df][0] * inv);
        o.y = f2b(oacc[df][1] * inv);
        o.z = f2b(oacc[df][2] * inv);
        o.w = f2b(oacc[df][3] * inv);
        *(ushort4*)(orow + (df << 4) + (lg << 2)) = o;
      }
      if (t != nt - 1) {  // switch to segment B
        qseg0 = qiB * 64;
        mrow = -1e30f;
        lrow = 0.f;
#pragma unroll
        for (int df = 0; df < 4; ++df)
#pragma unroll
          for (int i = 0; i < 4; ++i) oacc[df][i] = 0.f;
        const u16* qp = Qb + base + (size_t)(qseg0 + (w << 4) + l16) * DHEAD + (lg << 3);
        qf[0] = *(const bf16x8*)qp;
        qf[1] = *(const bf16x8*)(qp + 32);
      }
    }

    if (pre) tile_barrier();
    cur ^= 1;
  }
}

extern "C" void kernel_launch(void* const* d_in, const int* in_sizes, int n_in,
                              void* d_out, int out_size, void* d_ws, size_t ws_size,
                              hipStream_t stream) {
  const float* x = (const float*)d_in[0];
  const float* w_in = (const float*)d_in[1];
  const float* b_in = (const float*)d_in[2];
  const float* w_out = (const float*)d_in[3];
  const float* b_out = (const float*)d_in[4];
  const int* amask = (const int*)d_in[5];
  float* out = (float*)d_out;

  u16* xb = (u16*)d_ws;
  u16* wib = xb + (size_t)MROWS * DEMB;
  u16* wob = wib + (size_t)3 * DEMB * DEMB;
  u16* Qb = wob + (size_t)DEMB * DEMB;
  u16* Kb = Qb + (size_t)MROWS * DEMB;
  u16* Vtg = Kb + (size_t)MROWS * DEMB;  // transposed V: [bh][d][s]
  u16* Ab = xb;  // attn output reuses x-bf16 region

  cvt3_f32_bf16<<<2048, 256, 0, stream>>>(x, MROWS * DEMB, w_in, 3 * DEMB * DEMB,
                                          w_out, DEMB * DEMB, xb, wib, wob);

  gemm_nt<0><<<dim3(24, 32), 256, 0, stream>>>(xb, wib, b_in, DEMB, 3 * DEMB,
                                               Qb, Kb, Vtg, nullptr);
  attn_fwd<<<512, 256, 0, stream>>>(Qb, Kb, Vtg, Ab, amask);
  gemm_nt<1><<<dim3(8, 32), 256, 0, stream>>>(Ab, wob, b_out, DEMB, DEMB,
                                              nullptr, nullptr, nullptr, out);
}